// Round 1
// baseline (865.903 us; speedup 1.0000x reference)
//
#include <hip/hip_runtime.h>

#define H_ 128
#define W_ 128
#define B_ 8
#define CIN 64
#define COUT 128
#define KK 9
#define HW_ (H_*W_)
#define PIXB 32
#define CCH 4

// ---------------- Kernel 1: offset = conv3x3(x, w_off) + b_off ----------------
// One thread per output pixel (b,h,w), all 18 output channels accumulated.
// Weight reads are wave-uniform -> compiler emits s_load (constant cache).
__global__ __launch_bounds__(256) void offset_conv_kernel(
    const float* __restrict__ x, const float* __restrict__ w_off,
    const float* __restrict__ b_off, float* __restrict__ offset) {
  int pid = blockIdx.x * 256 + threadIdx.x;  // over B*H*W
  int b = pid / HW_;
  int hw = pid % HW_;
  int h = hw / W_, w = hw % W_;

  float acc[18];
#pragma unroll
  for (int o = 0; o < 18; ++o) acc[o] = b_off[o];

  const float* xb = x + (size_t)b * CIN * HW_;
  for (int c = 0; c < CIN; ++c) {
    const float* xp = xb + c * HW_;
    float xv[9];
#pragma unroll
    for (int ky = 0; ky < 3; ++ky) {
      int y = h + ky - 1;
      bool vy = (y >= 0) && (y < H_);
#pragma unroll
      for (int kx = 0; kx < 3; ++kx) {
        int xx = w + kx - 1;
        bool v = vy && (xx >= 0) && (xx < W_);
        xv[ky * 3 + kx] = v ? xp[y * W_ + xx] : 0.f;
      }
    }
#pragma unroll
    for (int o = 0; o < 18; ++o) {
      const float* wr = w_off + ((size_t)o * CIN + c) * 9;
      acc[o] += xv[0] * wr[0] + xv[1] * wr[1] + xv[2] * wr[2]
              + xv[3] * wr[3] + xv[4] * wr[4] + xv[5] * wr[5]
              + xv[6] * wr[6] + xv[7] * wr[7] + xv[8] * wr[8];
    }
  }
  float* op = offset + (size_t)b * 18 * HW_ + hw;
#pragma unroll
  for (int o = 0; o < 18; ++o) op[(size_t)o * HW_] = acc[o];
}

// ---------------- Kernel 2: deformable conv main ----------------
// Block = 256 threads handles 32 consecutive pixels (one row segment) x 128 oc.
// Phase A: bilinear metadata (4 corner idx + 4 weights) per (pixel,kk) in LDS.
// Phase B: loop c in chunks of 4: gather S[cc][kk][pix] to LDS, stage W
// transposed [cc][kk][oc] to LDS, then float4-vectorized FMA accumulation.
__global__ __launch_bounds__(256) void dcn_main_kernel(
    const float* __restrict__ x, const float* __restrict__ offset,
    const float* __restrict__ w_core, float* __restrict__ out) {
  __shared__ int4   m_idx[PIXB * KK];
  __shared__ float4 m_w[PIXB * KK];
  __shared__ float  s_lds[CCH * KK * PIXB];   // (cc*9+kk)*32 + pix
  __shared__ float  w_lds[CCH * KK * COUT];   // (cc*9+kk)*128 + oc

  const int tid = threadIdx.x;
  const int p0 = blockIdx.x * PIXB;      // 32 pixels, same (b, ho) row
  const int b = p0 / HW_;
  const int hw0 = p0 % HW_;
  const int ho = hw0 / W_;
  const int wo0 = hw0 % W_;

  // Phase A: metadata for 288 (pixel, tap) entries
  for (int e = tid; e < PIXB * KK; e += 256) {
    int pix = e / KK, kk = e % KK;
    int ky = kk / 3, kx = kk % 3;
    int wo = wo0 + pix;
    const float* offp = offset + ((size_t)b * 18 + kk * 2) * HW_ + ho * W_ + wo;
    float ody = offp[0];
    float odx = offp[HW_];
    float py = (float)(ho - 1 + ky) + ody;
    float px = (float)(wo - 1 + kx) + odx;
    float y0f = floorf(py), x0f = floorf(px);
    float dy = py - y0f, dx = px - x0f;
    int y0 = (int)y0f, x0 = (int)x0f;
    int y1 = y0 + 1, x1 = x0 + 1;
    bool vy0 = (y0 >= 0) && (y0 < H_);
    bool vy1 = (y1 >= 0) && (y1 < H_);
    bool vx0 = (x0 >= 0) && (x0 < W_);
    bool vx1 = (x1 >= 0) && (x1 < W_);
    int cy0 = y0 < 0 ? 0 : (y0 > H_ - 1 ? H_ - 1 : y0);
    int cy1 = y1 < 0 ? 0 : (y1 > H_ - 1 ? H_ - 1 : y1);
    int cx0 = x0 < 0 ? 0 : (x0 > W_ - 1 ? W_ - 1 : x0);
    int cx1 = x1 < 0 ? 0 : (x1 > W_ - 1 ? W_ - 1 : x1);
    m_idx[e] = make_int4(cy0 * W_ + cx0, cy0 * W_ + cx1,
                         cy1 * W_ + cx0, cy1 * W_ + cx1);
    m_w[e] = make_float4((1.f - dy) * (1.f - dx) * ((vy0 && vx0) ? 1.f : 0.f),
                         (1.f - dy) * dx         * ((vy0 && vx1) ? 1.f : 0.f),
                         dy * (1.f - dx)         * ((vy1 && vx0) ? 1.f : 0.f),
                         dy * dx                 * ((vy1 && vx1) ? 1.f : 0.f));
  }
  __syncthreads();

  float acc[4][4];
#pragma unroll
  for (int i = 0; i < 4; ++i)
#pragma unroll
    for (int j = 0; j < 4; ++j) acc[i][j] = 0.f;

  const int pgrp = tid & 7;    // 8 pixel groups of 4
  const int ocg = tid >> 3;    // 32 oc groups of 4

  for (int c0 = 0; c0 < CIN; c0 += CCH) {
    // gather S: 1152 entries
    for (int e = tid; e < CCH * KK * PIXB; e += 256) {
      int cc = e / (KK * PIXB);
      int r = e % (KK * PIXB);
      int kk = r >> 5;
      int pix = r & 31;
      int m = pix * KK + kk;
      const float* xp = x + ((size_t)(b * CIN + c0 + cc)) * HW_;
      int4 id = m_idx[m];
      float4 wt = m_w[m];
      s_lds[e] = wt.x * xp[id.x] + wt.y * xp[id.y] +
                 wt.z * xp[id.z] + wt.w * xp[id.w];
    }
    // stage W transposed: 4608 entries
    for (int e = tid; e < CCH * KK * COUT; e += 256) {
      int cc = e / (KK * COUT);
      int r = e % (KK * COUT);
      int kk = r >> 7;
      int oc = r & 127;
      w_lds[e] = w_core[(size_t)oc * (CIN * KK) + (c0 + cc) * KK + kk];
    }
    __syncthreads();

#pragma unroll
    for (int cc = 0; cc < CCH; ++cc) {
#pragma unroll
      for (int kk = 0; kk < KK; ++kk) {
        float4 sv = *(const float4*)&s_lds[(cc * KK + kk) * PIXB + pgrp * 4];
        float4 wv = *(const float4*)&w_lds[(cc * KK + kk) * COUT + ocg * 4];
        acc[0][0] += sv.x * wv.x; acc[0][1] += sv.x * wv.y;
        acc[0][2] += sv.x * wv.z; acc[0][3] += sv.x * wv.w;
        acc[1][0] += sv.y * wv.x; acc[1][1] += sv.y * wv.y;
        acc[1][2] += sv.y * wv.z; acc[1][3] += sv.y * wv.w;
        acc[2][0] += sv.z * wv.x; acc[2][1] += sv.z * wv.y;
        acc[2][2] += sv.z * wv.z; acc[2][3] += sv.z * wv.w;
        acc[3][0] += sv.w * wv.x; acc[3][1] += sv.w * wv.y;
        acc[3][2] += sv.w * wv.z; acc[3][3] += sv.w * wv.w;
      }
    }
    __syncthreads();
  }

  // store: per oc, 4 consecutive pixels -> float4
  int wo = wo0 + pgrp * 4;
  float* op = out + ((size_t)(b * COUT + ocg * 4)) * HW_ + ho * W_ + wo;
#pragma unroll
  for (int j = 0; j < 4; ++j) {
    float4 v = make_float4(acc[0][j], acc[1][j], acc[2][j], acc[3][j]);
    *(float4*)(op + (size_t)j * HW_) = v;
  }
}

extern "C" void kernel_launch(void* const* d_in, const int* in_sizes, int n_in,
                              void* d_out, int out_size, void* d_ws, size_t ws_size,
                              hipStream_t stream) {
  const float* x      = (const float*)d_in[0];
  const float* w_off  = (const float*)d_in[1];
  const float* b_off  = (const float*)d_in[2];
  const float* w_core = (const float*)d_in[3];
  float* offset = (float*)d_out;                        // [8,18,128,128]
  float* y      = (float*)d_out + (size_t)B_ * 18 * HW_; // [8,128,128,128]

  offset_conv_kernel<<<(B_ * HW_) / 256, 256, 0, stream>>>(x, w_off, b_off, offset);
  dcn_main_kernel<<<(B_ * HW_) / PIXB, 256, 0, stream>>>(x, offset, w_core, y);
}

// Round 2
// 596.658 us; speedup vs baseline: 1.4513x; 1.4513x over previous
//
#include <hip/hip_runtime.h>

#define H_ 128
#define W_ 128
#define B_ 8
#define CIN 64
#define COUT 128
#define KK 9
#define HW_ (H_*W_)
#define PIXB 32

typedef __bf16 bf16x8 __attribute__((ext_vector_type(8)));
typedef float f32x16 __attribute__((ext_vector_type(16)));
typedef unsigned short u16x8 __attribute__((ext_vector_type(8)));

__device__ inline unsigned short f2bf(float f) {
  unsigned int u = __builtin_bit_cast(unsigned int, f);
  u += 0x7FFFu + ((u >> 16) & 1u);   // RNE
  return (unsigned short)(u >> 16);
}
__device__ inline float bf2f(unsigned short h) {
  unsigned int u = ((unsigned int)h) << 16;
  return __builtin_bit_cast(float, u);
}

// ---------------- Kernel 1: offset = conv3x3(x, w_off) + b_off ----------------
__global__ __launch_bounds__(256) void offset_conv_kernel(
    const float* __restrict__ x, const float* __restrict__ w_off,
    const float* __restrict__ b_off, float* __restrict__ offset) {
  int pid = blockIdx.x * 256 + threadIdx.x;
  int b = pid / HW_;
  int hw = pid % HW_;
  int h = hw / W_, w = hw % W_;

  float acc[18];
#pragma unroll
  for (int o = 0; o < 18; ++o) acc[o] = b_off[o];

  const float* xb = x + (size_t)b * CIN * HW_;
  for (int c = 0; c < CIN; ++c) {
    const float* xp = xb + c * HW_;
    float xv[9];
#pragma unroll
    for (int ky = 0; ky < 3; ++ky) {
      int y = h + ky - 1;
      bool vy = (y >= 0) && (y < H_);
#pragma unroll
      for (int kx = 0; kx < 3; ++kx) {
        int xx = w + kx - 1;
        bool v = vy && (xx >= 0) && (xx < W_);
        xv[ky * 3 + kx] = v ? xp[y * W_ + xx] : 0.f;
      }
    }
#pragma unroll
    for (int o = 0; o < 18; ++o) {
      const float* wr = w_off + ((size_t)o * CIN + c) * 9;
      acc[o] += xv[0] * wr[0] + xv[1] * wr[1] + xv[2] * wr[2]
              + xv[3] * wr[3] + xv[4] * wr[4] + xv[5] * wr[5]
              + xv[6] * wr[6] + xv[7] * wr[7] + xv[8] * wr[8];
    }
  }
  float* op = offset + (size_t)b * 18 * HW_ + hw;
#pragma unroll
  for (int o = 0; o < 18; ++o) op[(size_t)o * HW_] = acc[o];
}

// ---------------- Kernel 0: transpose w_core into MFMA-ready bf16 layout ------
// WT[cc0][kk][h][oc][i] = bf16(w_core[oc][cc0*16+h*8+i][kk]); 73728 entries.
__global__ __launch_bounds__(256) void wt_kernel(
    const float* __restrict__ w_core, unsigned short* __restrict__ WT) {
  int g = blockIdx.x * 256 + threadIdx.x;
  int i  = g & 7;
  int oc = (g >> 3) & 127;
  int h  = (g >> 10) & 1;
  int t  = g >> 11;
  int kk = t % 9;
  int cc0 = t / 9;
  int c = cc0 * 16 + h * 8 + i;
  WT[g] = f2bf(w_core[(size_t)oc * (CIN * KK) + c * KK + kk]);
}

// ---------------- Kernel 2: deformable conv main (MFMA) ----------------
// Block: 256 thr = 4 waves, tile 32 pix x 128 oc. Wave w owns oc [32w,32w+32).
// K = (kk,c) chunks of 16 channels. S split hi/lo bf16 (fp32-accurate),
// W single bf16. Per chunk per wave: 9 kk x 2 MFMA 32x32x16.
__global__ __launch_bounds__(256) void dcn_main_mfma(
    const float* __restrict__ x, const float* __restrict__ offset,
    const unsigned short* __restrict__ WT, float* __restrict__ out) {
  __shared__ int4   m_idx[PIXB * KK];
  __shared__ float4 m_w[PIXB * KK];
  __shared__ alignas(16) unsigned short s_hi[KK * 2 * PIXB * 8];   // 9216 B
  __shared__ alignas(16) unsigned short s_lo[KK * 2 * PIXB * 8];   // 9216 B
  __shared__ alignas(16) unsigned short w_lds[KK * 2 * COUT * 8];  // 36864 B

  const int tid = threadIdx.x;
  const int lane = tid & 63;
  const int wid = tid >> 6;
  const int p0 = blockIdx.x * PIXB;
  const int b = p0 / HW_;
  const int hw0 = p0 % HW_;
  const int ho = hw0 / W_;
  const int wo0 = hw0 % W_;

  // Phase A: bilinear metadata per (pixel, tap)
  for (int e = tid; e < PIXB * KK; e += 256) {
    int pix = e / KK, kk = e % KK;
    int ky = kk / 3, kx = kk % 3;
    int wo = wo0 + pix;
    const float* offp = offset + ((size_t)b * 18 + kk * 2) * HW_ + ho * W_ + wo;
    float ody = offp[0];
    float odx = offp[HW_];
    float py = (float)(ho - 1 + ky) + ody;
    float px = (float)(wo - 1 + kx) + odx;
    float y0f = floorf(py), x0f = floorf(px);
    float dy = py - y0f, dx = px - x0f;
    int y0 = (int)y0f, x0 = (int)x0f;
    int y1 = y0 + 1, x1 = x0 + 1;
    bool vy0 = (y0 >= 0) && (y0 < H_);
    bool vy1 = (y1 >= 0) && (y1 < H_);
    bool vx0 = (x0 >= 0) && (x0 < W_);
    bool vx1 = (x1 >= 0) && (x1 < W_);
    int cy0 = y0 < 0 ? 0 : (y0 > H_ - 1 ? H_ - 1 : y0);
    int cy1 = y1 < 0 ? 0 : (y1 > H_ - 1 ? H_ - 1 : y1);
    int cx0 = x0 < 0 ? 0 : (x0 > W_ - 1 ? W_ - 1 : x0);
    int cx1 = x1 < 0 ? 0 : (x1 > W_ - 1 ? W_ - 1 : x1);
    m_idx[e] = make_int4(cy0 * W_ + cx0, cy0 * W_ + cx1,
                         cy1 * W_ + cx0, cy1 * W_ + cx1);
    m_w[e] = make_float4((1.f - dy) * (1.f - dx) * ((vy0 && vx0) ? 1.f : 0.f),
                         (1.f - dy) * dx         * ((vy0 && vx1) ? 1.f : 0.f),
                         dy * (1.f - dx)         * ((vy1 && vx0) ? 1.f : 0.f),
                         dy * dx                 * ((vy1 && vx1) ? 1.f : 0.f));
  }
  __syncthreads();

  f32x16 acc = {0.f,0.f,0.f,0.f,0.f,0.f,0.f,0.f,
                0.f,0.f,0.f,0.f,0.f,0.f,0.f,0.f};

  const int gpix = tid >> 3;   // gather: this thread's pixel (0..31)
  const int gi = tid & 7;      // gather: channel-low bits (i)
  const int h_frag = lane >> 5;
  const int col = lane & 31;

  for (int cc0 = 0; cc0 < 4; ++cc0) {
    // ---- gather S (hi/lo bf16) ----
#pragma unroll
    for (int kk = 0; kk < KK; ++kk) {
      int4 id = m_idx[gpix * KK + kk];
      float4 wt = m_w[gpix * KK + kk];
#pragma unroll
      for (int hh = 0; hh < 2; ++hh) {
        int c = cc0 * 16 + hh * 8 + gi;
        const float* xp = x + ((size_t)(b * CIN + c)) * HW_;
        float v = wt.x * xp[id.x] + wt.y * xp[id.y] +
                  wt.z * xp[id.z] + wt.w * xp[id.w];
        unsigned short hi = f2bf(v);
        int e = ((kk * 2 + hh) * PIXB + gpix) * 8 + gi;
        s_hi[e] = hi;
        s_lo[e] = f2bf(v - bf2f(hi));
      }
    }
    // ---- stage W (coalesced 16B copies from pre-transposed WT) ----
    {
      const u16x8* src = (const u16x8*)(WT + (size_t)cc0 * (KK * 2 * COUT * 8));
      u16x8* dst = (u16x8*)w_lds;
#pragma unroll
      for (int k = 0; k < 9; ++k) {
        int s = tid + k * 256;
        dst[s] = src[s];
      }
    }
    __syncthreads();

    // ---- MFMA: 9 kk x (hi + lo) ----
#pragma unroll
    for (int kk = 0; kk < KK; ++kk) {
      int sb = ((kk * 2 + h_frag) * PIXB + col) * 8;
      int wb = ((kk * 2 + h_frag) * COUT + wid * 32 + col) * 8;
      bf16x8 a  = __builtin_bit_cast(bf16x8, *(const u16x8*)&w_lds[wb]);
      bf16x8 bh = __builtin_bit_cast(bf16x8, *(const u16x8*)&s_hi[sb]);
      bf16x8 bl = __builtin_bit_cast(bf16x8, *(const u16x8*)&s_lo[sb]);
      acc = __builtin_amdgcn_mfma_f32_32x32x16_bf16(a, bh, acc, 0, 0, 0);
      acc = __builtin_amdgcn_mfma_f32_32x32x16_bf16(a, bl, acc, 0, 0, 0);
    }
    __syncthreads();
  }

  // ---- store: D layout col=lane&31 (pix), row=(r&3)+8*(r>>2)+4*(lane>>5) ----
  float* op = out + ((size_t)b * COUT) * HW_ + ho * W_ + wo0 + col;
  const int ocb = wid * 32 + 4 * h_frag;
#pragma unroll
  for (int r = 0; r < 16; ++r) {
    int oc = ocb + (r & 3) + 8 * (r >> 2);
    op[(size_t)oc * HW_] = acc[r];
  }
}

extern "C" void kernel_launch(void* const* d_in, const int* in_sizes, int n_in,
                              void* d_out, int out_size, void* d_ws, size_t ws_size,
                              hipStream_t stream) {
  const float* x      = (const float*)d_in[0];
  const float* w_off  = (const float*)d_in[1];
  const float* b_off  = (const float*)d_in[2];
  const float* w_core = (const float*)d_in[3];
  float* offset = (float*)d_out;                         // [8,18,128,128]
  float* y      = (float*)d_out + (size_t)B_ * 18 * HW_; // [8,128,128,128]
  unsigned short* WT = (unsigned short*)d_ws;            // 73728 bf16 = 147456 B

  wt_kernel<<<288, 256, 0, stream>>>(w_core, WT);
  offset_conv_kernel<<<(B_ * HW_) / 256, 256, 0, stream>>>(x, w_off, b_off, offset);
  dcn_main_mfma<<<(B_ * HW_) / PIXB, 256, 0, stream>>>(x, offset, WT, y);
}

// Round 7
// 551.331 us; speedup vs baseline: 1.5706x; 1.0822x over previous
//
#include <hip/hip_runtime.h>

#define H_ 128
#define W_ 128
#define B_ 8
#define CIN 64
#define COUT 128
#define KK 9
#define HW_ (H_*W_)
#define PIXB 32

typedef __bf16 bf16x8 __attribute__((ext_vector_type(8)));
typedef float f32x16 __attribute__((ext_vector_type(16)));
typedef unsigned short u16x8 __attribute__((ext_vector_type(8)));

__device__ inline unsigned short f2bf(float f) {
  unsigned int u = __builtin_bit_cast(unsigned int, f);
  u += 0x7FFFu + ((u >> 16) & 1u);   // RNE
  return (unsigned short)(u >> 16);
}
__device__ inline float bf2f(unsigned short h) {
  unsigned int u = ((unsigned int)h) << 16;
  return __builtin_bit_cast(float, u);
}

// ---------------- Kernel 1: offset = conv3x3(x, w_off) + b_off ----------------
// One thread per 2 consecutive output pixels; weight reads wave-uniform (s_load).
__global__ __launch_bounds__(256) void offset_conv_kernel(
    const float* __restrict__ x, const float* __restrict__ w_off,
    const float* __restrict__ b_off, float* __restrict__ offset) {
  int pid = blockIdx.x * 256 + threadIdx.x;   // over B*HW/2
  int b = pid / (HW_ / 2);
  int q = pid % (HW_ / 2);
  int h = q / (W_ / 2);
  int w2 = (q % (W_ / 2)) * 2;

  float acc[18][2];
#pragma unroll
  for (int o = 0; o < 18; ++o) { acc[o][0] = b_off[o]; acc[o][1] = b_off[o]; }

  const float* xb = x + (size_t)b * CIN * HW_;
  for (int c = 0; c < CIN; ++c) {
    const float* xp = xb + c * HW_;
    float xv[3][4];   // cols w2-1 .. w2+2
#pragma unroll
    for (int r = 0; r < 3; ++r) {
      int y = h + r - 1;
      bool vy = (y >= 0) && (y < H_);
      float2 mid = vy ? *(const float2*)&xp[y * W_ + w2] : make_float2(0.f, 0.f);
      xv[r][0] = (vy && w2 > 0) ? xp[y * W_ + w2 - 1] : 0.f;
      xv[r][1] = mid.x;
      xv[r][2] = mid.y;
      xv[r][3] = (vy && w2 + 2 < W_) ? xp[y * W_ + w2 + 2] : 0.f;
    }
#pragma unroll
    for (int o = 0; o < 18; ++o) {
      const float* wr = w_off + ((size_t)o * CIN + c) * 9;
#pragma unroll
      for (int p = 0; p < 2; ++p) {
        acc[o][p] += xv[0][p] * wr[0] + xv[0][p + 1] * wr[1] + xv[0][p + 2] * wr[2]
                   + xv[1][p] * wr[3] + xv[1][p + 1] * wr[4] + xv[1][p + 2] * wr[5]
                   + xv[2][p] * wr[6] + xv[2][p + 1] * wr[7] + xv[2][p + 2] * wr[8];
      }
    }
  }
  float* op = offset + (size_t)b * 18 * HW_ + h * W_ + w2;
#pragma unroll
  for (int o = 0; o < 18; ++o)
    *(float2*)(op + (size_t)o * HW_) = make_float2(acc[o][0], acc[o][1]);
}

// ---------------- Kernel 0: transpose w_core into MFMA-ready bf16 layout ------
// WT[cc0][kk][h][oc][i] = bf16(w_core[oc][cc0*16+h*8+i][kk]); 73728 entries.
__global__ __launch_bounds__(256) void wt_kernel(
    const float* __restrict__ w_core, unsigned short* __restrict__ WT) {
  int g = blockIdx.x * 256 + threadIdx.x;
  int i  = g & 7;
  int oc = (g >> 3) & 127;
  int h  = (g >> 10) & 1;
  int t  = g >> 11;
  int kk = t % 9;
  int cc0 = t / 9;
  int c = cc0 * 16 + h * 8 + i;
  WT[g] = f2bf(w_core[(size_t)oc * (CIN * KK) + c * KK + kk]);
}

// ---------------- Kernel 2: deformable conv main (MFMA) ----------------
// Block: 256 thr = 4 waves, tile 32 pix x 128 oc. Wave w owns oc [32w,32w+32).
// LDS = 25.3 KB (metadata + S hi/lo only) -> 5-6 blocks/CU. A-fragments are
// loaded straight from pre-transposed WT (coalesced, L2-resident).
__global__ __launch_bounds__(256, 5) void dcn_main_mfma(
    const float* __restrict__ x, const float* __restrict__ offset,
    const unsigned short* __restrict__ WT, float* __restrict__ out) {
  __shared__ ushort4 m_idx[PIXB * KK];                             // 2304 B
  __shared__ float4  m_w[PIXB * KK];                               // 4608 B
  __shared__ alignas(16) unsigned short s_hi[KK * 2 * PIXB * 8];   // 9216 B
  __shared__ alignas(16) unsigned short s_lo[KK * 2 * PIXB * 8];   // 9216 B

  const int tid = threadIdx.x;
  const int lane = tid & 63;
  const int wid = tid >> 6;
  const int p0 = blockIdx.x * PIXB;
  const int b = p0 / HW_;
  const int hw0 = p0 % HW_;
  const int ho = hw0 / W_;
  const int wo0 = hw0 % W_;

  // Phase A: bilinear metadata per (pixel, tap)
  for (int e = tid; e < PIXB * KK; e += 256) {
    int pix = e / KK, kk = e % KK;
    int ky = kk / 3, kx = kk % 3;
    int wo = wo0 + pix;
    const float* offp = offset + ((size_t)b * 18 + kk * 2) * HW_ + ho * W_ + wo;
    float ody = offp[0];
    float odx = offp[HW_];
    float py = (float)(ho - 1 + ky) + ody;
    float px = (float)(wo - 1 + kx) + odx;
    float y0f = floorf(py), x0f = floorf(px);
    float dy = py - y0f, dx = px - x0f;
    int y0 = (int)y0f, x0 = (int)x0f;
    int y1 = y0 + 1, x1 = x0 + 1;
    bool vy0 = (y0 >= 0) && (y0 < H_);
    bool vy1 = (y1 >= 0) && (y1 < H_);
    bool vx0 = (x0 >= 0) && (x0 < W_);
    bool vx1 = (x1 >= 0) && (x1 < W_);
    int cy0 = y0 < 0 ? 0 : (y0 > H_ - 1 ? H_ - 1 : y0);
    int cy1 = y1 < 0 ? 0 : (y1 > H_ - 1 ? H_ - 1 : y1);
    int cx0 = x0 < 0 ? 0 : (x0 > W_ - 1 ? W_ - 1 : x0);
    int cx1 = x1 < 0 ? 0 : (x1 > W_ - 1 ? W_ - 1 : x1);
    m_idx[e] = make_ushort4((unsigned short)(cy0 * W_ + cx0),
                            (unsigned short)(cy0 * W_ + cx1),
                            (unsigned short)(cy1 * W_ + cx0),
                            (unsigned short)(cy1 * W_ + cx1));
    m_w[e] = make_float4((1.f - dy) * (1.f - dx) * ((vy0 && vx0) ? 1.f : 0.f),
                         (1.f - dy) * dx         * ((vy0 && vx1) ? 1.f : 0.f),
                         dy * (1.f - dx)         * ((vy1 && vx0) ? 1.f : 0.f),
                         dy * dx                 * ((vy1 && vx1) ? 1.f : 0.f));
  }
  __syncthreads();

  f32x16 acc = {0.f,0.f,0.f,0.f,0.f,0.f,0.f,0.f,
                0.f,0.f,0.f,0.f,0.f,0.f,0.f,0.f};

  const int gpix = tid >> 3;   // gather: this thread's pixel (0..31)
  const int gi = tid & 7;      // gather: channel-low bits (i)
  const int h_frag = lane >> 5;
  const int col = lane & 31;

  // Per-wave A-fragment base in WT (vec-of-8 units)
  const u16x8* wbase = (const u16x8*)WT + (size_t)(h_frag * COUT + wid * 32 + col);

  for (int cc0 = 0; cc0 < 4; ++cc0) {
    // ---- gather S (hi/lo bf16) ----
#pragma unroll
    for (int kk = 0; kk < KK; ++kk) {
      ushort4 id = m_idx[gpix * KK + kk];
      float4 wt = m_w[gpix * KK + kk];
#pragma unroll
      for (int hh = 0; hh < 2; ++hh) {
        int c = cc0 * 16 + hh * 8 + gi;
        const float* xp = x + ((size_t)(b * CIN + c)) * HW_;
        float v = wt.x * xp[id.x] + wt.y * xp[id.y] +
                  wt.z * xp[id.z] + wt.w * xp[id.w];
        unsigned short hi = f2bf(v);
        int e = ((kk * 2 + hh) * PIXB + gpix) * 8 + gi;
        s_hi[e] = hi;
        s_lo[e] = f2bf(v - bf2f(hi));
      }
    }
    __syncthreads();

    // ---- MFMA: 9 kk x (hi + lo), A from global WT (coalesced, L2-hit) ----
    const u16x8* wp = wbase + (size_t)cc0 * (KK * 2 * COUT);
#pragma unroll
    for (int kk = 0; kk < KK; ++kk) {
      int sb = ((kk * 2 + h_frag) * PIXB + col) * 8;
      bf16x8 a  = __builtin_bit_cast(bf16x8, wp[(size_t)kk * 2 * COUT]);
      bf16x8 bh = __builtin_bit_cast(bf16x8, *(const u16x8*)&s_hi[sb]);
      bf16x8 bl = __builtin_bit_cast(bf16x8, *(const u16x8*)&s_lo[sb]);
      acc = __builtin_amdgcn_mfma_f32_32x32x16_bf16(a, bh, acc, 0, 0, 0);
      acc = __builtin_amdgcn_mfma_f32_32x32x16_bf16(a, bl, acc, 0, 0, 0);
    }
    __syncthreads();
  }

  // ---- store: D layout col=lane&31 (pix), row=(r&3)+8*(r>>2)+4*(lane>>5) ----
  float* op = out + ((size_t)b * COUT) * HW_ + ho * W_ + wo0 + col;
  const int ocb = wid * 32 + 4 * h_frag;
#pragma unroll
  for (int r = 0; r < 16; ++r) {
    int oc = ocb + (r & 3) + 8 * (r >> 2);
    op[(size_t)oc * HW_] = acc[r];
  }
}

extern "C" void kernel_launch(void* const* d_in, const int* in_sizes, int n_in,
                              void* d_out, int out_size, void* d_ws, size_t ws_size,
                              hipStream_t stream) {
  const float* x      = (const float*)d_in[0];
  const float* w_off  = (const float*)d_in[1];
  const float* b_off  = (const float*)d_in[2];
  const float* w_core = (const float*)d_in[3];
  float* offset = (float*)d_out;                         // [8,18,128,128]
  float* y      = (float*)d_out + (size_t)B_ * 18 * HW_; // [8,128,128,128]
  unsigned short* WT = (unsigned short*)d_ws;            // 73728 bf16 = 147456 B

  wt_kernel<<<288, 256, 0, stream>>>(w_core, WT);
  offset_conv_kernel<<<(B_ * HW_ / 2) / 256, 256, 0, stream>>>(x, w_off, b_off, offset);
  dcn_main_mfma<<<(B_ * HW_) / PIXB, 256, 0, stream>>>(x, offset, WT, y);
}

// Round 8
// 474.502 us; speedup vs baseline: 1.8249x; 1.1619x over previous
//
#include <hip/hip_runtime.h>

#define H_ 128
#define W_ 128
#define B_ 8
#define CIN 64
#define COUT 128
#define KK 9
#define HW_ (H_*W_)
#define PIXB 32

typedef __bf16 bf16x8 __attribute__((ext_vector_type(8)));
typedef float f32x16 __attribute__((ext_vector_type(16)));
typedef unsigned short u16x8 __attribute__((ext_vector_type(8)));

__device__ inline unsigned short f2bf(float f) {
  unsigned int u = __builtin_bit_cast(unsigned int, f);
  u += 0x7FFFu + ((u >> 16) & 1u);   // RNE
  return (unsigned short)(u >> 16);
}
__device__ inline float bf2f(unsigned short h) {
  unsigned int u = ((unsigned int)h) << 16;
  return __builtin_bit_cast(float, u);
}

// ---------------- Kernel 0a: transpose w_core into MFMA-ready bf16 layout ----
// WT[cc0][kk][h][oc][i] = bf16(w_core[oc][cc0*16+h*8+i][kk]); 73728 entries.
__global__ __launch_bounds__(256) void wt_kernel(
    const float* __restrict__ w_core, unsigned short* __restrict__ WT) {
  int g = blockIdx.x * 256 + threadIdx.x;
  int i  = g & 7;
  int oc = (g >> 3) & 127;
  int h  = (g >> 10) & 1;
  int t  = g >> 11;
  int kk = t % 9;
  int cc0 = t / 9;
  int c = cc0 * 16 + h * 8 + i;
  WT[g] = f2bf(w_core[(size_t)oc * (CIN * KK) + c * KK + kk]);
}

// ---------------- Kernel 0b: w_off -> padded-32-row hi/lo bf16 layout --------
// WT2[cc0][kk][h][oc32][i]; rows >=18 are zero. 18432 entries per plane.
__global__ __launch_bounds__(256) void wt2_kernel(
    const float* __restrict__ w_off, unsigned short* __restrict__ WT2h,
    unsigned short* __restrict__ WT2l) {
  int g = blockIdx.x * 256 + threadIdx.x;   // 18432 total
  int i  = g & 7;
  int oc = (g >> 3) & 31;
  int h  = (g >> 8) & 1;
  int t  = g >> 9;        // 0..35
  int kk = t % 9;
  int cc0 = t / 9;
  int c = cc0 * 16 + h * 8 + i;
  float v = (oc < 18) ? w_off[((size_t)oc * CIN + c) * 9 + kk] : 0.f;
  unsigned short hi = f2bf(v);
  WT2h[g] = hi;
  WT2l[g] = f2bf(v - bf2f(hi));
}

// ---------------- Kernel 1: offset conv via MFMA ----------------
// 1 wave/block, 32 px x 32 oc (18 real). Integer-tap gather is coalesced
// (32 consecutive pixels per half-wave). 3-term hi/lo MFMA ~= fp32 exact.
__global__ __launch_bounds__(64) void offset_mfma_kernel(
    const float* __restrict__ x, const unsigned short* __restrict__ WT2h,
    const unsigned short* __restrict__ WT2l, const float* __restrict__ b_off,
    float* __restrict__ offset) {
  __shared__ alignas(16) unsigned short sb_hi[KK * 2 * PIXB * 8];   // 9216 B
  __shared__ alignas(16) unsigned short sb_lo[KK * 2 * PIXB * 8];   // 9216 B

  const int lane = threadIdx.x;
  const int p0 = blockIdx.x * PIXB;
  const int b = p0 / HW_;
  const int hw0 = p0 % HW_;
  const int ho = hw0 / W_;
  const int wo0 = hw0 % W_;
  const int pix = lane & 31;      // also MFMA col
  const int cpart = lane >> 5;    // also MFMA h_frag

  f32x16 acc;
#pragma unroll
  for (int r = 0; r < 16; ++r) {
    int oc = (r & 3) + 8 * (r >> 2) + 4 * cpart;
    acc[r] = (oc < 18) ? b_off[oc] : 0.f;
  }

  for (int cc0 = 0; cc0 < 4; ++cc0) {
    // ---- gather exact x taps, hi/lo split ----
#pragma unroll
    for (int kk = 0; kk < KK; ++kk) {
      int ky = kk / 3, kx = kk % 3;
      int y = ho + ky - 1;
      int xx = wo0 + pix + kx - 1;
      bool v = (y >= 0) && (y < H_) && (xx >= 0) && (xx < W_);
      int yc = y < 0 ? 0 : (y > H_ - 1 ? H_ - 1 : y);
      int xc = xx < 0 ? 0 : (xx > W_ - 1 ? W_ - 1 : xx);
#pragma unroll
      for (int hh = 0; hh < 2; ++hh) {
#pragma unroll
        for (int q = 0; q < 4; ++q) {
          int gi = cpart * 4 + q;
          int c = cc0 * 16 + hh * 8 + gi;
          float val = v ? x[((size_t)(b * CIN + c)) * HW_ + yc * W_ + xc] : 0.f;
          unsigned short hi = f2bf(val);
          int e = ((kk * 2 + hh) * PIXB + pix) * 8 + gi;
          sb_hi[e] = hi;
          sb_lo[e] = f2bf(val - bf2f(hi));
        }
      }
    }
    __syncthreads();

    // ---- MFMA: 9 kk x 3 terms ----
#pragma unroll
    for (int kk = 0; kk < KK; ++kk) {
      int sb = ((kk * 2 + cpart) * PIXB + pix) * 8;
      size_t av = (size_t)(((cc0 * 9 + kk) * 2 + cpart) * 32 + pix);
      bf16x8 ah = __builtin_bit_cast(bf16x8, ((const u16x8*)WT2h)[av]);
      bf16x8 al = __builtin_bit_cast(bf16x8, ((const u16x8*)WT2l)[av]);
      bf16x8 bh = __builtin_bit_cast(bf16x8, *(const u16x8*)&sb_hi[sb]);
      bf16x8 bl = __builtin_bit_cast(bf16x8, *(const u16x8*)&sb_lo[sb]);
      acc = __builtin_amdgcn_mfma_f32_32x32x16_bf16(ah, bh, acc, 0, 0, 0);
      acc = __builtin_amdgcn_mfma_f32_32x32x16_bf16(ah, bl, acc, 0, 0, 0);
      acc = __builtin_amdgcn_mfma_f32_32x32x16_bf16(al, bh, acc, 0, 0, 0);
    }
    __syncthreads();
  }

  float* op = offset + (size_t)b * 18 * HW_ + ho * W_ + wo0 + pix;
#pragma unroll
  for (int r = 0; r < 16; ++r) {
    int oc = (r & 3) + 8 * (r >> 2) + 4 * cpart;
    if (oc < 18) op[(size_t)oc * HW_] = acc[r];
  }
}

// ---------------- Kernel 2: deformable conv main (MFMA) ----------------
// Block: 256 thr = 4 waves, tile 32 pix x 128 oc. Gather lanes are PIXEL-major
// (lane&31 = pixel): adjacent pixels sample adjacent locations -> each
// half-wave's 32 addresses land in ~2-3 cache lines (vs 64 with channel-major).
__global__ __launch_bounds__(256, 5) void dcn_main_mfma(
    const float* __restrict__ x, const float* __restrict__ offset,
    const unsigned short* __restrict__ WT, float* __restrict__ out) {
  __shared__ ushort4 m_idx[PIXB * KK];                             // 2304 B
  __shared__ float4  m_w[PIXB * KK];                               // 4608 B
  __shared__ alignas(16) unsigned short s_hi[KK * 2 * PIXB * 8];   // 9216 B
  __shared__ alignas(16) unsigned short s_lo[KK * 2 * PIXB * 8];   // 9216 B

  const int tid = threadIdx.x;
  const int lane = tid & 63;
  const int wid = tid >> 6;
  const int p0 = blockIdx.x * PIXB;
  const int b = p0 / HW_;
  const int hw0 = p0 % HW_;
  const int ho = hw0 / W_;
  const int wo0 = hw0 % W_;

  // Phase A: bilinear metadata per (pixel, tap)
  for (int e = tid; e < PIXB * KK; e += 256) {
    int pix = e / KK, kk = e % KK;
    int ky = kk / 3, kx = kk % 3;
    int wo = wo0 + pix;
    const float* offp = offset + ((size_t)b * 18 + kk * 2) * HW_ + ho * W_ + wo;
    float ody = offp[0];
    float odx = offp[HW_];
    float py = (float)(ho - 1 + ky) + ody;
    float px = (float)(wo - 1 + kx) + odx;
    float y0f = floorf(py), x0f = floorf(px);
    float dy = py - y0f, dx = px - x0f;
    int y0 = (int)y0f, x0 = (int)x0f;
    int y1 = y0 + 1, x1 = x0 + 1;
    bool vy0 = (y0 >= 0) && (y0 < H_);
    bool vy1 = (y1 >= 0) && (y1 < H_);
    bool vx0 = (x0 >= 0) && (x0 < W_);
    bool vx1 = (x1 >= 0) && (x1 < W_);
    int cy0 = y0 < 0 ? 0 : (y0 > H_ - 1 ? H_ - 1 : y0);
    int cy1 = y1 < 0 ? 0 : (y1 > H_ - 1 ? H_ - 1 : y1);
    int cx0 = x0 < 0 ? 0 : (x0 > W_ - 1 ? W_ - 1 : x0);
    int cx1 = x1 < 0 ? 0 : (x1 > W_ - 1 ? W_ - 1 : x1);
    m_idx[e] = make_ushort4((unsigned short)(cy0 * W_ + cx0),
                            (unsigned short)(cy0 * W_ + cx1),
                            (unsigned short)(cy1 * W_ + cx0),
                            (unsigned short)(cy1 * W_ + cx1));
    m_w[e] = make_float4((1.f - dy) * (1.f - dx) * ((vy0 && vx0) ? 1.f : 0.f),
                         (1.f - dy) * dx         * ((vy0 && vx1) ? 1.f : 0.f),
                         dy * (1.f - dx)         * ((vy1 && vx0) ? 1.f : 0.f),
                         dy * dx                 * ((vy1 && vx1) ? 1.f : 0.f));
  }
  __syncthreads();

  f32x16 acc = {0.f,0.f,0.f,0.f,0.f,0.f,0.f,0.f,
                0.f,0.f,0.f,0.f,0.f,0.f,0.f,0.f};

  const int gpix = tid & 31;   // gather: pixel (lane-major -> coalesced)
  const int gi = tid >> 5;     // gather: channel-low bits (i)
  const int h_frag = lane >> 5;
  const int col = lane & 31;

  // Per-wave A-fragment base in WT (vec-of-8 units)
  const u16x8* wbase = (const u16x8*)WT + (size_t)(h_frag * COUT + wid * 32 + col);

  for (int cc0 = 0; cc0 < 4; ++cc0) {
    // ---- gather S (hi/lo bf16) ----
#pragma unroll
    for (int kk = 0; kk < KK; ++kk) {
      ushort4 id = m_idx[gpix * KK + kk];
      float4 wt = m_w[gpix * KK + kk];
#pragma unroll
      for (int hh = 0; hh < 2; ++hh) {
        int c = cc0 * 16 + hh * 8 + gi;
        const float* xp = x + ((size_t)(b * CIN + c)) * HW_;
        float v = wt.x * xp[id.x] + wt.y * xp[id.y] +
                  wt.z * xp[id.z] + wt.w * xp[id.w];
        unsigned short hi = f2bf(v);
        int e = ((kk * 2 + hh) * PIXB + gpix) * 8 + gi;
        s_hi[e] = hi;
        s_lo[e] = f2bf(v - bf2f(hi));
      }
    }
    __syncthreads();

    // ---- MFMA: 9 kk x (hi + lo), A from global WT (coalesced, L2-hit) ----
    const u16x8* wp = wbase + (size_t)cc0 * (KK * 2 * COUT);
#pragma unroll
    for (int kk = 0; kk < KK; ++kk) {
      int sb = ((kk * 2 + h_frag) * PIXB + col) * 8;
      bf16x8 a  = __builtin_bit_cast(bf16x8, wp[(size_t)kk * 2 * COUT]);
      bf16x8 bh = __builtin_bit_cast(bf16x8, *(const u16x8*)&s_hi[sb]);
      bf16x8 bl = __builtin_bit_cast(bf16x8, *(const u16x8*)&s_lo[sb]);
      acc = __builtin_amdgcn_mfma_f32_32x32x16_bf16(a, bh, acc, 0, 0, 0);
      acc = __builtin_amdgcn_mfma_f32_32x32x16_bf16(a, bl, acc, 0, 0, 0);
    }
    __syncthreads();
  }

  // ---- store: D layout col=lane&31 (pix), row=(r&3)+8*(r>>2)+4*(lane>>5) ----
  float* op = out + ((size_t)b * COUT) * HW_ + ho * W_ + wo0 + col;
  const int ocb = wid * 32 + 4 * h_frag;
#pragma unroll
  for (int r = 0; r < 16; ++r) {
    int oc = ocb + (r & 3) + 8 * (r >> 2);
    op[(size_t)oc * HW_] = acc[r];
  }
}

extern "C" void kernel_launch(void* const* d_in, const int* in_sizes, int n_in,
                              void* d_out, int out_size, void* d_ws, size_t ws_size,
                              hipStream_t stream) {
  const float* x      = (const float*)d_in[0];
  const float* w_off  = (const float*)d_in[1];
  const float* b_off  = (const float*)d_in[2];
  const float* w_core = (const float*)d_in[3];
  float* offset = (float*)d_out;                         // [8,18,128,128]
  float* y      = (float*)d_out + (size_t)B_ * 18 * HW_; // [8,128,128,128]
  unsigned short* WT   = (unsigned short*)d_ws;          // 73728 u16
  unsigned short* WT2h = WT + 73728;                     // 18432 u16
  unsigned short* WT2l = WT2h + 18432;                   // 18432 u16

  wt_kernel<<<288, 256, 0, stream>>>(w_core, WT);
  wt2_kernel<<<72, 256, 0, stream>>>(w_off, WT2h, WT2l);
  offset_mfma_kernel<<<(B_ * HW_) / PIXB, 64, 0, stream>>>(x, WT2h, WT2l, b_off, offset);
  dcn_main_mfma<<<(B_ * HW_) / PIXB, 256, 0, stream>>>(x, offset, WT, y);
}